// Round 2
// baseline (291.907 us; speedup 1.0000x reference)
//
#include <hip/hip_runtime.h>

#define W   4096
#define NT  256
#define PT  (W / NT)   // 16 contiguous slots per thread

__global__ __launch_bounds__(NT) void extrema_nms_kernel(
    const float* __restrict__ x,
    const int*   __restrict__ dist_p,
    float*       __restrict__ out)
{
    const int sig = blockIdx.x;
    const float* xg = x + (size_t)sig * W;
    float*       og = out + (size_t)sig * W;
    const int dist = *dist_p;

    __shared__ float xs[W];                 // 16 KB
    __shared__ unsigned long long key[W];   // 32 KB; 0 = not live

    const int tid = threadIdx.x;

    // Zero output and stage x.
    for (int i = tid; i < W; i += NT) {
        og[i] = 0.0f;
        xs[i] = xg[i];
    }
    __syncthreads();

    // Extrema mask -> packed priority key over contiguous owned slots.
    // key = (abs_bits << 32) | (W-1-i): descending |x|, ties -> smaller index
    // first (matches JAX stable argsort). Keys are unique; 0 = dead.
    const int base = tid * PT;
    for (int j = 0; j < PT; ++j) {
        int i = base + j;
        float xi = xs[i];
        bool right = (i < W - 1) ? (xs[i + 1] > xi) : false; // pad-right 0 -> false
        bool left  = (i > 0)     ? (xi <= xs[i - 1]) : true; // pad-left  0 -> true
        bool s     = (xi <= 0.0f);
        bool valley = right && left && s;
        bool peak   = (!right) && (!left) && (!s);
        unsigned int ab = __float_as_uint(xi) & 0x7fffffffu;
        key[i] = (valley || peak)
                   ? ((((unsigned long long)ab) << 32) |
                      (unsigned long long)(unsigned int)(W - 1 - i))
                   : 0ULL;
    }
    __syncthreads();

    // Parallel-exact greedy NMS:
    // round: keep every live candidate that is the strict max of its
    // +/-dist window (keepers are provably > dist apart), then kill all
    // live candidates in keepers' windows. Identical output to the
    // sequential greedy scan; converges when a round finds no keeper.
    for (;;) {
        unsigned keepmask = 0u;
        for (int j = 0; j < PT; ++j) {
            int i = base + j;
            unsigned long long mk = key[i];
            if (mk == 0ULL) continue;
            int lo = i - dist; lo = lo < 0 ? 0 : lo;
            int hi = i + dist; hi = hi > (W - 1) ? (W - 1) : hi;
            bool isMax = true;
            for (int q = lo; q <= hi; ++q) {
                if (key[q] > mk) { isMax = false; break; }  // early-exit
            }
            if (isMax) keepmask |= (1u << j);
        }
        // barrier + block-wide "any keeper this round?"
        int any = __syncthreads_count((int)(keepmask != 0u));
        if (any == 0) break;   // no keepers -> no live candidates remain

        if (keepmask) {
            for (int j = 0; j < PT; ++j) {
                if (keepmask & (1u << j)) {
                    int p = base + j;
                    og[p] = xs[p];                       // emit kept extremum
                    int lo = p - dist; lo = lo < 0 ? 0 : lo;
                    int hi = p + dist; hi = hi > (W - 1) ? (W - 1) : hi;
                    for (int q = lo; q <= hi; ++q) key[q] = 0ULL;  // kill window
                }
            }
        }
        __syncthreads();
    }
}

extern "C" void kernel_launch(void* const* d_in, const int* in_sizes, int n_in,
                              void* d_out, int out_size, void* d_ws, size_t ws_size,
                              hipStream_t stream) {
    const float* x      = (const float*)d_in[0];
    const int*   dist_p = (const int*)d_in[1];
    float*       out    = (float*)d_out;
    const int nsig = in_sizes[0] / W;   // 128 signals of length 4096
    hipLaunchKernelGGL(extrema_nms_kernel, dim3(nsig), dim3(NT), 0, stream,
                       x, dist_p, out);
}

// Round 3
// 22.073 us; speedup vs baseline: 13.2245x; 13.2245x over previous
//
#include <hip/hip_runtime.h>

typedef unsigned long long u64;

#define W    4096
#define NT   256
#define PT   16          // contiguous elements per thread
#define NCH  128         // chunks of size 32 (== dist fast path)
#define D32  32

__global__ __launch_bounds__(NT) void extrema_nms_kernel(
    const float* __restrict__ x,
    const int*   __restrict__ dist_p,
    float*       __restrict__ out)
{
    const int sig = blockIdx.x;
    const float* xg = x + (size_t)sig * W;
    float*       og = out + (size_t)sig * W;
    const int dist = *dist_p;

    __shared__ float xs[W];          // 16 KB, read-only after init
    __shared__ u64   halfmax[NT];    // 2 KB   (fast path)
    __shared__ int   killflag[NCH];  // 512 B  (fast path)
    __shared__ u64   key[W];         // 32 KB  (generic fallback only)
    __shared__ u64   red[NT / 64];   //        (generic fallback only)

    const int tid = threadIdx.x;

    // stage x, zero output
    for (int i = tid; i < W; i += NT) { xs[i] = xg[i]; og[i] = 0.0f; }
    __syncthreads();

    if (dist == D32) {
        // ---------- fast path: chunk(=dist)-decomposed parallel greedy NMS ----------
        const int c    = tid >> 1;      // own chunk (2 threads per chunk)
        const int base = tid * PT;      // first owned element

        // keys in registers. key = (abs_bits<<32) | (W-1-i):
        // descending |x|, ties -> smaller index (matches stable argsort).
        // low 32 bits encode position, so a chunk max knows its own argmax.
        u64 kr[PT];
        #pragma unroll
        for (int j = 0; j < PT; ++j) {
            const int i = base + j;
            const float xi = xs[i];
            const bool right = (i < W - 1) ? (xs[i + 1] > xi) : false; // pad-right -> false
            const bool left  = (i > 0)     ? (xi <= xs[i - 1]) : true; // pad-left  -> true
            const bool s = (xi <= 0.0f);
            const bool valley = right && left && s;
            const bool peak   = !right && !left && !s;
            const unsigned ab = __float_as_uint(xi) & 0x7fffffffu;
            kr[j] = (valley || peak) ? (((u64)ab << 32) | (u64)(unsigned)(W - 1 - i)) : 0ull;
        }
        u64 mx = 0ull;
        #pragma unroll
        for (int j = 0; j < PT; ++j) if (kr[j] > mx) mx = kr[j];

        for (;;) {
            halfmax[tid] = mx;
            if (tid < NCH) killflag[tid] = 0;
            __syncthreads();                               // A

            // chunk maxes of c-1, c, c+1 (each = max of two half-maxes)
            u64 Mm = 0ull, Mp = 0ull, h0, h1;
            if (c > 0) {
                h0 = halfmax[2 * c - 2]; h1 = halfmax[2 * c - 1];
                Mm = h0 > h1 ? h0 : h1;
            }
            h0 = halfmax[2 * c]; h1 = halfmax[2 * c + 1];
            const u64 Mc = h0 > h1 ? h0 : h1;
            if (c < NCH - 1) {
                h0 = halfmax[2 * c + 2]; h1 = halfmax[2 * c + 3];
                Mp = h0 > h1 ? h0 : h1;
            }
            const int jm = (W - 1) - (int)(Mm & 0xffffffffu); // c-1 candidate pos
            const int jc = (W - 1) - (int)(Mc & 0xffffffffu); // own  candidate pos
            const int jp = (W - 1) - (int)(Mp & 0xffffffffu); // c+1 candidate pos

            // push-kill: do my elements suppress a neighbor chunk's candidate?
            // (own chunk's candidate can't be beaten by own chunk: it IS the max)
            if (Mm != 0ull && mx > Mm) {
                #pragma unroll
                for (int j = 0; j < PT; ++j) {
                    const int i = base + j;
                    if (kr[j] > Mm && (i - jm) <= D32) killflag[c - 1] = 1;
                }
            }
            if (Mp != 0ull && mx > Mp) {
                #pragma unroll
                for (int j = 0; j < PT; ++j) {
                    const int i = base + j;
                    if (kr[j] > Mp && (jp - i) <= D32) killflag[c + 1] = 1;
                }
            }
            __syncthreads();                               // C

            const bool keep_m = (Mm != 0ull) && (killflag[c - 1] == 0); // Mm==0 when c==0
            const bool keep_c = (Mc != 0ull) && (killflag[c] == 0);
            const bool keep_p = (Mp != 0ull) && (killflag[c + 1] == 0); // Mp==0 when c==NCH-1

            // emit own-chunk keeper if its position is in my half
            if (keep_c && jc >= base && jc < base + PT)
                og[jc] = xs[jc];

            // kill own register keys inside keeper windows (gated on overlap)
            bool changed = false;
            if (keep_m && jm >= base - D32 && jm <= base + PT - 1 + D32) {
                #pragma unroll
                for (int j = 0; j < PT; ++j)
                    if (kr[j] && (unsigned)(base + j - jm + D32) <= 2u * D32) { kr[j] = 0ull; changed = true; }
            }
            if (keep_c && jc >= base - D32 && jc <= base + PT - 1 + D32) {
                #pragma unroll
                for (int j = 0; j < PT; ++j)
                    if (kr[j] && (unsigned)(base + j - jc + D32) <= 2u * D32) { kr[j] = 0ull; changed = true; }
            }
            if (keep_p && jp >= base - D32 && jp <= base + PT - 1 + D32) {
                #pragma unroll
                for (int j = 0; j < PT; ++j)
                    if (kr[j] && (unsigned)(base + j - jp + D32) <= 2u * D32) { kr[j] = 0ull; changed = true; }
            }
            if (changed) {
                mx = 0ull;
                #pragma unroll
                for (int j = 0; j < PT; ++j) if (kr[j] > mx) mx = kr[j];
            }

            const int nkeep = __syncthreads_count((int)keep_c); // D + termination
            if (nkeep == 0) break;  // no keeper => no live candidates remain
        }
    } else {
        // ---------- generic fallback (any dist): proven R1 serial-greedy ----------
        for (int i = tid; i < W; i += NT) {
            const float xi = xs[i];
            const bool right = (i < W - 1) ? (xs[i + 1] > xi) : false;
            const bool left  = (i > 0)     ? (xi <= xs[i - 1]) : true;
            const bool s = (xi <= 0.0f);
            const bool valley = right && left && s;
            const bool peak   = !right && !left && !s;
            const unsigned ab = __float_as_uint(xi) & 0x7fffffffu;
            key[i] = (valley || peak) ? (((u64)ab << 32) | (u64)(unsigned)(W - 1 - i)) : 0ull;
        }
        __syncthreads();

        for (;;) {
            u64 m = 0ull;
            #pragma unroll
            for (int j = 0; j < W / NT; ++j) {
                const u64 k = key[tid + j * NT];
                if (k > m) m = k;
            }
            #pragma unroll
            for (int off = 32; off > 0; off >>= 1) {
                const u64 o = __shfl_down(m, off, 64);
                if (o > m) m = o;
            }
            if ((tid & 63) == 0) red[tid >> 6] = m;
            __syncthreads();
            if (tid == 0) {
                u64 w0 = red[0];
                #pragma unroll
                for (int w2 = 1; w2 < NT / 64; ++w2) if (red[w2] > w0) w0 = red[w2];
                red[0] = w0;
            }
            __syncthreads();
            const u64 win = red[0];
            if (win == 0ull) break;

            const int p = (W - 1) - (int)(win & 0xffffffffu);
            if (tid == 0) og[p] = xs[p];

            int lo = p - dist; lo = lo < 0 ? 0 : lo;
            int hi = p + dist; hi = hi > (W - 1) ? (W - 1) : hi;
            for (int j = lo + tid; j <= hi; j += NT) key[j] = 0ull;
            __syncthreads();
        }
    }
}

extern "C" void kernel_launch(void* const* d_in, const int* in_sizes, int n_in,
                              void* d_out, int out_size, void* d_ws, size_t ws_size,
                              hipStream_t stream) {
    const float* x      = (const float*)d_in[0];
    const int*   dist_p = (const int*)d_in[1];
    float*       out    = (float*)d_out;
    const int nsig = in_sizes[0] / W;   // 128 signals of length 4096
    hipLaunchKernelGGL(extrema_nms_kernel, dim3(nsig), dim3(NT), 0, stream,
                       x, dist_p, out);
}

// Round 4
// 21.385 us; speedup vs baseline: 13.6498x; 1.0322x over previous
//
#include <hip/hip_runtime.h>

typedef unsigned long long u64;

#define W    4096
#define NT   256
#define PT   16          // contiguous elements per thread
#define NCH  128         // chunks of size 32 (== dist fast path)
#define D32  32

__global__ __launch_bounds__(NT) void extrema_nms_kernel(
    const float* __restrict__ x,
    const int*   __restrict__ dist_p,
    float*       __restrict__ out)
{
    const int sig = blockIdx.x;
    const float* xg = x + (size_t)sig * W;
    float*       og = out + (size_t)sig * W;
    const int dist = *dist_p;

    __shared__ float xs[W];          // 16 KB, read-only after init
    __shared__ u64   halfmax[NT];    // 2 KB
    __shared__ int   killflag[NCH];  // 512 B, round-stamped (no re-zeroing)
    __shared__ int   kept[NCH];      // 512 B, keeper position+1, 0 = none
    __shared__ u64   key[W];         // 32 KB (generic fallback only)
    __shared__ u64   red[NT / 64];   // (generic fallback only)

    const int tid = threadIdx.x;

    // coalesced float4 staging of x into LDS
    {
        const float4* xg4 = (const float4*)xg;
        float4*       xs4 = (float4*)xs;
        #pragma unroll
        for (int v = tid; v < W / 4; v += NT) xs4[v] = xg4[v];
    }
    if (tid < NCH) { killflag[tid] = 0; kept[tid] = 0; }
    __syncthreads();

    if (dist == D32) {
        // ---------- fast path: chunk(=dist)-decomposed parallel greedy NMS ----------
        const int c    = tid >> 1;      // own chunk (2 threads per chunk)
        const int base = tid * PT;      // first owned element

        // keys in registers. key = (abs_bits<<32) | (W-1-i):
        // descending |x|, ties -> smaller index (matches stable argsort).
        u64 kr[PT];
        #pragma unroll
        for (int j = 0; j < PT; ++j) {
            const int i = base + j;
            const float xi = xs[i];
            const bool right = (i < W - 1) ? (xs[i + 1] > xi) : false; // pad-right -> false
            const bool left  = (i > 0)     ? (xi <= xs[i - 1]) : true; // pad-left  -> true
            const bool s = (xi <= 0.0f);
            const bool valley = right && left && s;
            const bool peak   = !right && !left && !s;
            const unsigned ab = __float_as_uint(xi) & 0x7fffffffu;
            kr[j] = (valley || peak) ? (((u64)ab << 32) | (u64)(unsigned)(W - 1 - i)) : 0ull;
        }
        u64 mx = 0ull;
        #pragma unroll
        for (int j = 0; j < PT; ++j) if (kr[j] > mx) mx = kr[j];

        // LDS-only round loop, 2 barriers per round.
        int r = 0;
        for (;;) {
            ++r;
            halfmax[tid] = mx;
            const int live = __syncthreads_count((int)(mx != 0ull)); // barrier 1
            if (live == 0) break;   // no live candidates anywhere -> done

            u64 Mm = 0ull, Mp = 0ull, h0, h1;
            if (c > 0) {
                h0 = halfmax[2 * c - 2]; h1 = halfmax[2 * c - 1];
                Mm = h0 > h1 ? h0 : h1;
            }
            h0 = halfmax[2 * c]; h1 = halfmax[2 * c + 1];
            const u64 Mc = h0 > h1 ? h0 : h1;
            if (c < NCH - 1) {
                h0 = halfmax[2 * c + 2]; h1 = halfmax[2 * c + 3];
                Mp = h0 > h1 ? h0 : h1;
            }
            const int jm = (W - 1) - (int)(Mm & 0xffffffffu);
            const int jc = (W - 1) - (int)(Mc & 0xffffffffu);
            const int jp = (W - 1) - (int)(Mp & 0xffffffffu);

            // push-kill: my live elements suppress neighbor-chunk candidates
            if (Mm != 0ull && mx > Mm) {
                #pragma unroll
                for (int j = 0; j < PT; ++j)
                    if (kr[j] > Mm && ((base + j) - jm) <= D32) killflag[c - 1] = r;
            }
            if (Mp != 0ull && mx > Mp) {
                #pragma unroll
                for (int j = 0; j < PT; ++j)
                    if (kr[j] > Mp && (jp - (base + j)) <= D32) killflag[c + 1] = r;
            }
            __syncthreads();                                          // barrier 2

            const bool keep_m = (Mm != 0ull) && (killflag[c - 1] != r);
            const bool keep_c = (Mc != 0ull) && (killflag[c]     != r);
            const bool keep_p = (Mp != 0ull) && (killflag[c + 1] != r);

            if (keep_c && (tid & 1) == 0) kept[c] = jc + 1;  // record keeper (LDS only)

            // kill own register keys inside keeper windows
            bool changed = false;
            if (keep_m && jm >= base - D32 && jm <= base + PT - 1 + D32) {
                #pragma unroll
                for (int j = 0; j < PT; ++j)
                    if (kr[j] && (unsigned)(base + j - jm + D32) <= 2u * D32) { kr[j] = 0ull; changed = true; }
            }
            if (keep_c && jc >= base - D32 && jc <= base + PT - 1 + D32) {
                #pragma unroll
                for (int j = 0; j < PT; ++j)
                    if (kr[j] && (unsigned)(base + j - jc + D32) <= 2u * D32) { kr[j] = 0ull; changed = true; }
            }
            if (keep_p && jp >= base - D32 && jp <= base + PT - 1 + D32) {
                #pragma unroll
                for (int j = 0; j < PT; ++j)
                    if (kr[j] && (unsigned)(base + j - jp + D32) <= 2u * D32) { kr[j] = 0ull; changed = true; }
            }
            if (changed) {
                mx = 0ull;
                #pragma unroll
                for (int j = 0; j < PT; ++j) if (kr[j] > mx) mx = kr[j];
            }
        }

        // single coalesced output pass (kept[] is final; break's barrier ordered it)
        {
            float4* og4 = (float4*)og;
            #pragma unroll
            for (int v = tid; v < W / 4; v += NT) {
                const int i = v * 4;
                const int k = kept[i >> 5] - 1;   // chunk of i (4-aligned block stays in one chunk)
                float4 o;
                o.x = (k == i    ) ? xs[i    ] : 0.0f;
                o.y = (k == i + 1) ? xs[i + 1] : 0.0f;
                o.z = (k == i + 2) ? xs[i + 2] : 0.0f;
                o.w = (k == i + 3) ? xs[i + 3] : 0.0f;
                og4[v] = o;
            }
        }
    } else {
        // ---------- generic fallback (any dist): proven R1 serial-greedy ----------
        for (int i = tid; i < W; i += NT) og[i] = 0.0f;
        for (int i = tid; i < W; i += NT) {
            const float xi = xs[i];
            const bool right = (i < W - 1) ? (xs[i + 1] > xi) : false;
            const bool left  = (i > 0)     ? (xi <= xs[i - 1]) : true;
            const bool s = (xi <= 0.0f);
            const bool valley = right && left && s;
            const bool peak   = !right && !left && !s;
            const unsigned ab = __float_as_uint(xi) & 0x7fffffffu;
            key[i] = (valley || peak) ? (((u64)ab << 32) | (u64)(unsigned)(W - 1 - i)) : 0ull;
        }
        __syncthreads();

        for (;;) {
            u64 m = 0ull;
            #pragma unroll
            for (int j = 0; j < W / NT; ++j) {
                const u64 k = key[tid + j * NT];
                if (k > m) m = k;
            }
            #pragma unroll
            for (int off = 32; off > 0; off >>= 1) {
                const u64 o = __shfl_down(m, off, 64);
                if (o > m) m = o;
            }
            if ((tid & 63) == 0) red[tid >> 6] = m;
            __syncthreads();
            if (tid == 0) {
                u64 w0 = red[0];
                #pragma unroll
                for (int w2 = 1; w2 < NT / 64; ++w2) if (red[w2] > w0) w0 = red[w2];
                red[0] = w0;
            }
            __syncthreads();
            const u64 win = red[0];
            if (win == 0ull) break;

            const int p = (W - 1) - (int)(win & 0xffffffffu);
            if (tid == 0) og[p] = xs[p];

            int lo = p - dist; lo = lo < 0 ? 0 : lo;
            int hi = p + dist; hi = hi > (W - 1) ? (W - 1) : hi;
            for (int j = lo + tid; j <= hi; j += NT) key[j] = 0ull;
            __syncthreads();
        }
    }
}

extern "C" void kernel_launch(void* const* d_in, const int* in_sizes, int n_in,
                              void* d_out, int out_size, void* d_ws, size_t ws_size,
                              hipStream_t stream) {
    const float* x      = (const float*)d_in[0];
    const int*   dist_p = (const int*)d_in[1];
    float*       out    = (float*)d_out;
    const int nsig = in_sizes[0] / W;   // 128 signals of length 4096
    hipLaunchKernelGGL(extrema_nms_kernel, dim3(nsig), dim3(NT), 0, stream,
                       x, dist_p, out);
}

// Round 5
// 19.797 us; speedup vs baseline: 14.7452x; 1.0802x over previous
//
#include <hip/hip_runtime.h>

typedef unsigned long long u64;

#define W    4096
#define NT   256
#define PT   16          // contiguous elements per thread
#define NCH  128         // chunks of size 32 (== dist fast path)
#define D32  32

__global__ __launch_bounds__(NT) void extrema_nms_kernel(
    const float* __restrict__ x,
    const int*   __restrict__ dist_p,
    float*       __restrict__ out)
{
    const int sig = blockIdx.x;
    const float* xg = x + (size_t)sig * W;
    float*       og = out + (size_t)sig * W;
    const int dist = *dist_p;

    __shared__ float xs[W];          // 16 KB, read-only after init
    __shared__ u64   HM[NT + 4];     // padded half-maxes: half h -> HM[h+2]; pads = 0
    __shared__ int   KF[NCH + 2];    // padded killflags: chunk c -> KF[c+1]; round-stamped
    __shared__ int   kept[NCH];      // keeper position+1, 0 = none
    __shared__ int   LF;             // round-stamped live flag
    __shared__ u64   key[W];         // 32 KB (generic fallback only)
    __shared__ u64   red[NT / 64];   // (generic fallback only)

    const int tid = threadIdx.x;

    // coalesced float4 staging of x into LDS
    {
        const float4* xg4 = (const float4*)xg;
        float4*       xs4 = (float4*)xs;
        #pragma unroll
        for (int v = tid; v < W / 4; v += NT) xs4[v] = xg4[v];
    }
    if (tid < 2) { HM[tid] = 0ull; HM[NT + 2 + tid] = 0ull; }  // edge pads, never rewritten
    if (tid < NCH + 2) KF[tid] = 0;
    if (tid < NCH) kept[tid] = 0;
    if (tid == 0) LF = 0;
    __syncthreads();

    if (dist == D32) {
        // ---------- fast path: chunk(=dist)-decomposed parallel greedy NMS ----------
        const int c    = tid >> 1;      // own chunk (2 threads per chunk)
        const int base = tid * PT;      // first owned element

        // keys in registers. key = (abs_bits<<32) | (W-1-i):
        // descending |x|, ties -> smaller index (matches stable argsort).
        u64 kr[PT];
        #pragma unroll
        for (int j = 0; j < PT; ++j) {
            const int i = base + j;
            const float xi = xs[i];
            const bool right = (i < W - 1) ? (xs[i + 1] > xi) : false; // pad-right -> false
            const bool left  = (i > 0)     ? (xi <= xs[i - 1]) : true; // pad-left  -> true
            const bool s = (xi <= 0.0f);
            const bool valley = right && left && s;
            const bool peak   = !right && !left && !s;
            const unsigned ab = __float_as_uint(xi) & 0x7fffffffu;
            kr[j] = (valley || peak) ? (((u64)ab << 32) | (u64)(unsigned)(W - 1 - i)) : 0ull;
        }
        u64 mx = 0ull;
        #pragma unroll
        for (int j = 0; j < PT; ++j) if (kr[j] > mx) mx = kr[j];

        // LDS-only round loop, exactly 2 barriers per round, no wgred.
        int r = 0;
        for (;;) {
            ++r;
            HM[tid + 2] = mx;
            if (mx != 0ull) LF = r;     // same-address store, one lane wins
            __syncthreads();                                   // B1
            const int live = LF;        // broadcast read
            // neighbor window: halves 2c-2 .. 2c+3 -> padded 2c .. 2c+5 (16B-aligned)
            const u64 h0 = HM[2 * c];
            const u64 h1 = HM[2 * c + 1];
            const u64 h2 = HM[2 * c + 2];
            const u64 h3 = HM[2 * c + 3];
            const u64 h4 = HM[2 * c + 4];
            const u64 h5 = HM[2 * c + 5];
            if (live != r) break;       // uniform: no live candidates anywhere

            const u64 Mm = h0 > h1 ? h0 : h1;   // chunk c-1 max (0 at edge via pads)
            const u64 Mc = h2 > h3 ? h2 : h3;   // own chunk max
            const u64 Mp = h4 > h5 ? h4 : h5;   // chunk c+1 max
            const int jm = (W - 1) - (int)(Mm & 0xffffffffu);
            const int jc = (W - 1) - (int)(Mc & 0xffffffffu);
            const int jp = (W - 1) - (int)(Mp & 0xffffffffu);

            // push-kill: my live elements suppress neighbor-chunk candidates
            if (Mm != 0ull && mx > Mm) {
                #pragma unroll
                for (int j = 0; j < PT; ++j)
                    if (kr[j] > Mm && ((base + j) - jm) <= D32) KF[c] = r;       // chunk c-1
            }
            if (Mp != 0ull && mx > Mp) {
                #pragma unroll
                for (int j = 0; j < PT; ++j)
                    if (kr[j] > Mp && (jp - (base + j)) <= D32) KF[c + 2] = r;   // chunk c+1
            }
            __syncthreads();                                   // B2
            const int kf0 = KF[c];
            const int kf1 = KF[c + 1];
            const int kf2 = KF[c + 2];
            const bool keep_m = (Mm != 0ull) && (kf0 != r);
            const bool keep_c = (Mc != 0ull) && (kf1 != r);
            const bool keep_p = (Mp != 0ull) && (kf2 != r);

            if (keep_c && (tid & 1) == 0) kept[c] = jc + 1;    // record keeper (LDS only)

            // kill own register keys inside keeper windows (gated on overlap)
            bool changed = false;
            if (keep_m && jm >= base - D32 && jm <= base + PT - 1 + D32) {
                #pragma unroll
                for (int j = 0; j < PT; ++j)
                    if (kr[j] && (unsigned)(base + j - jm + D32) <= 2u * D32) { kr[j] = 0ull; changed = true; }
            }
            if (keep_c && jc >= base - D32 && jc <= base + PT - 1 + D32) {
                #pragma unroll
                for (int j = 0; j < PT; ++j)
                    if (kr[j] && (unsigned)(base + j - jc + D32) <= 2u * D32) { kr[j] = 0ull; changed = true; }
            }
            if (keep_p && jp >= base - D32 && jp <= base + PT - 1 + D32) {
                #pragma unroll
                for (int j = 0; j < PT; ++j)
                    if (kr[j] && (unsigned)(base + j - jp + D32) <= 2u * D32) { kr[j] = 0ull; changed = true; }
            }
            if (changed) {
                mx = 0ull;
                #pragma unroll
                for (int j = 0; j < PT; ++j) if (kr[j] > mx) mx = kr[j];
            }
        }

        // single coalesced output pass (kept[] ordered by the break's barrier B1)
        {
            float4* og4 = (float4*)og;
            #pragma unroll
            for (int v = tid; v < W / 4; v += NT) {
                const int i = v * 4;
                const int k = kept[i >> 5] - 1;   // 4-aligned block stays in one chunk
                float4 o;
                o.x = (k == i    ) ? xs[i    ] : 0.0f;
                o.y = (k == i + 1) ? xs[i + 1] : 0.0f;
                o.z = (k == i + 2) ? xs[i + 2] : 0.0f;
                o.w = (k == i + 3) ? xs[i + 3] : 0.0f;
                og4[v] = o;
            }
        }
    } else {
        // ---------- generic fallback (any dist): proven R1 serial-greedy ----------
        for (int i = tid; i < W; i += NT) og[i] = 0.0f;
        for (int i = tid; i < W; i += NT) {
            const float xi = xs[i];
            const bool right = (i < W - 1) ? (xs[i + 1] > xi) : false;
            const bool left  = (i > 0)     ? (xi <= xs[i - 1]) : true;
            const bool s = (xi <= 0.0f);
            const bool valley = right && left && s;
            const bool peak   = !right && !left && !s;
            const unsigned ab = __float_as_uint(xi) & 0x7fffffffu;
            key[i] = (valley || peak) ? (((u64)ab << 32) | (u64)(unsigned)(W - 1 - i)) : 0ull;
        }
        __syncthreads();

        for (;;) {
            u64 m = 0ull;
            #pragma unroll
            for (int j = 0; j < W / NT; ++j) {
                const u64 k = key[tid + j * NT];
                if (k > m) m = k;
            }
            #pragma unroll
            for (int off = 32; off > 0; off >>= 1) {
                const u64 o = __shfl_down(m, off, 64);
                if (o > m) m = o;
            }
            if ((tid & 63) == 0) red[tid >> 6] = m;
            __syncthreads();
            if (tid == 0) {
                u64 w0 = red[0];
                #pragma unroll
                for (int w2 = 1; w2 < NT / 64; ++w2) if (red[w2] > w0) w0 = red[w2];
                red[0] = w0;
            }
            __syncthreads();
            const u64 win = red[0];
            if (win == 0ull) break;

            const int p = (W - 1) - (int)(win & 0xffffffffu);
            if (tid == 0) og[p] = xs[p];

            int lo = p - dist; lo = lo < 0 ? 0 : lo;
            int hi = p + dist; hi = hi > (W - 1) ? (W - 1) : hi;
            for (int j = lo + tid; j <= hi; j += NT) key[j] = 0ull;
            __syncthreads();
        }
    }
}

extern "C" void kernel_launch(void* const* d_in, const int* in_sizes, int n_in,
                              void* d_out, int out_size, void* d_ws, size_t ws_size,
                              hipStream_t stream) {
    const float* x      = (const float*)d_in[0];
    const int*   dist_p = (const int*)d_in[1];
    float*       out    = (float*)d_out;
    const int nsig = in_sizes[0] / W;   // 128 signals of length 4096
    hipLaunchKernelGGL(extrema_nms_kernel, dim3(nsig), dim3(NT), 0, stream,
                       x, dist_p, out);
}

// Round 6
// 16.174 us; speedup vs baseline: 18.0479x; 1.2240x over previous
//
#include <hip/hip_runtime.h>

typedef unsigned long long u64;

#define W    4096
#define NT   256
#define PT   16          // contiguous elements per thread
#define NCH  128         // chunks of size 32 (== dist fast path)
#define D32  32
#define PROBE 1          // round-count side-channel via bank-conflict counter

__global__ __launch_bounds__(NT) void extrema_nms_kernel(
    const float* __restrict__ x,
    const int*   __restrict__ dist_p,
    float*       __restrict__ out)
{
    const int sig = blockIdx.x;
    const float* xg = x + (size_t)sig * W;
    float*       og = out + (size_t)sig * W;
    const int dist = *dist_p;

    __shared__ __align__(16) float xs[W];       // 16 KB, read-only after init
    __shared__ __align__(16) u64   HM[NT + 4];  // padded half-maxes; pads = 0
    __shared__ int   KF[NCH + 2];               // padded killflags, round-stamped
    __shared__ int   kept[NCH];                 // keeper position+1, 0 = none
    __shared__ int   LF;                        // round-stamped live flag
    __shared__ __align__(16) u64   key[W];      // (generic fallback only)
    __shared__ u64   red[NT / 64];              // (generic fallback only)

    const int tid = threadIdx.x;

    // coalesced float4 staging of x into LDS
    {
        const float4* xg4 = (const float4*)xg;
        float4*       xs4 = (float4*)xs;
        #pragma unroll
        for (int v = tid; v < W / 4; v += NT) xs4[v] = xg4[v];
    }
    if (tid < 2) { HM[tid] = 0ull; HM[NT + 2 + tid] = 0ull; }  // edge pads
    if (tid < NCH + 2) KF[tid] = 0;
    if (tid < NCH) kept[tid] = 0;
    if (tid == 0) LF = 0;
    __syncthreads();

    if (dist == D32) {
        // ---------- fast path: chunk(=dist)-decomposed parallel greedy NMS ----------
        const int c    = tid >> 1;      // own chunk (2 threads per chunk)
        const int base = tid * PT;      // first owned element

        // extrema keys built from registers (explicit float4 loads, no rescans)
        u64 kr[PT];
        {
            const float4* xs4 = (const float4*)xs;
            const int b4 = tid * 4;
            const float4 q0 = xs4[b4], q1 = xs4[b4 + 1], q2 = xs4[b4 + 2], q3 = xs4[b4 + 3];
            float f[PT + 2];
            f[1] = q0.x; f[2] = q0.y; f[3] = q0.z; f[4] = q0.w;
            f[5] = q1.x; f[6] = q1.y; f[7] = q1.z; f[8] = q1.w;
            f[9] = q2.x; f[10] = q2.y; f[11] = q2.z; f[12] = q2.w;
            f[13] = q3.x; f[14] = q3.y; f[15] = q3.z; f[16] = q3.w;
            f[0]      = (base > 0)       ? xs[base - 1]  : __int_as_float(0x7f800000); // +inf -> left=true at i=0
            f[PT + 1] = (base + PT < W)  ? xs[base + PT] : q3.w;                        // x==x -> right=false at i=W-1
            #pragma unroll
            for (int j = 0; j < PT; ++j) {
                const float xi = f[j + 1];
                const bool right = f[j + 2] > xi;   // (x[i+1]-x[i]) > 0, pad-right -> false
                const bool left  = xi <= f[j];      // (x[i]-x[i-1]) <= 0, pad-left -> true
                const bool s = (xi <= 0.0f);
                const bool valley = right && left && s;
                const bool peak   = !right && !left && !s;
                const unsigned ab = __float_as_uint(xi) & 0x7fffffffu;
                kr[j] = (valley || peak)
                          ? (((u64)ab << 32) | (u64)(unsigned)(W - 1 - base - j)) : 0ull;
            }
        }
        u64 mx = 0ull;
        #pragma unroll
        for (int j = 0; j < PT; ++j) if (kr[j] > mx) mx = kr[j];

        // LDS-only round loop, 2 barriers per round.
        int r = 0;
        for (;;) {
            ++r;
            HM[tid + 2] = mx;
            const u64 bal = __ballot(mx != 0ull);
            if ((tid & 63) == 0 && bal) LF = r;    // <=1 store per wave
            __syncthreads();                                   // B1
            const int live = LF;
            const u64 h0 = HM[2 * c];
            const u64 h1 = HM[2 * c + 1];
            const u64 h2 = HM[2 * c + 2];
            const u64 h3 = HM[2 * c + 3];
            const u64 h4 = HM[2 * c + 4];
            const u64 h5 = HM[2 * c + 5];
            if (live != r) break;       // uniform: no live candidates anywhere

#if PROBE
            // round-count side-channel: 64 lanes -> one bank (stride 128 B).
            // SQ_LDS_BANK_CONFLICT ~= 128 blocks * depth * ~45cy. Remove later.
            if (tid < 64) {
                volatile float* vx = xs;
                float p = vx[tid * 32];
                asm volatile("" :: "v"(p));
            }
#endif

            const u64 Mm = h0 > h1 ? h0 : h1;   // chunk c-1 max (0 at edges via pads)
            const u64 Mc = h2 > h3 ? h2 : h3;   // own chunk max
            const u64 Mp = h4 > h5 ? h4 : h5;   // chunk c+1 max
            const int jm = (W - 1) - (int)(Mm & 0xffffffffu);
            const int jc = (W - 1) - (int)(Mc & 0xffffffffu);
            const int jp = (W - 1) - (int)(Mp & 0xffffffffu);

            // push-kill: my live elements suppress neighbor-chunk candidates
            if (Mm != 0ull && mx > Mm) {
                #pragma unroll
                for (int j = 0; j < PT; ++j)
                    if (kr[j] > Mm && ((base + j) - jm) <= D32) KF[c] = r;       // chunk c-1
            }
            if (Mp != 0ull && mx > Mp) {
                #pragma unroll
                for (int j = 0; j < PT; ++j)
                    if (kr[j] > Mp && (jp - (base + j)) <= D32) KF[c + 2] = r;   // chunk c+1
            }
            __syncthreads();                                   // B2
            const int kf0 = KF[c];
            const int kf1 = KF[c + 1];
            const int kf2 = KF[c + 2];
            const bool keep_m = (Mm != 0ull) && (kf0 != r);
            const bool keep_c = (Mc != 0ull) && (kf1 != r);
            const bool keep_p = (Mp != 0ull) && (kf2 != r);

            if (keep_c && (tid & 1) == 0) kept[c] = jc + 1;    // record keeper

            // kill own register keys inside keeper windows (skip if all mine dead)
            if (mx != 0ull) {
                bool changed = false;
                if (keep_m && jm >= base - D32 && jm <= base + PT - 1 + D32) {
                    const int tm = base - jm + D32;
                    #pragma unroll
                    for (int j = 0; j < PT; ++j)
                        if ((unsigned)(tm + j) <= 2u * D32) kr[j] = 0ull;
                    changed = true;
                }
                if (keep_c && jc >= base - D32 && jc <= base + PT - 1 + D32) {
                    const int tc = base - jc + D32;
                    #pragma unroll
                    for (int j = 0; j < PT; ++j)
                        if ((unsigned)(tc + j) <= 2u * D32) kr[j] = 0ull;
                    changed = true;
                }
                if (keep_p && jp >= base - D32 && jp <= base + PT - 1 + D32) {
                    const int tp = base - jp + D32;
                    #pragma unroll
                    for (int j = 0; j < PT; ++j)
                        if ((unsigned)(tp + j) <= 2u * D32) kr[j] = 0ull;
                    changed = true;
                }
                if (changed) {
                    mx = 0ull;
                    #pragma unroll
                    for (int j = 0; j < PT; ++j) if (kr[j] > mx) mx = kr[j];
                }
            }
        }

        // single coalesced output pass (kept[] ordered by the break's barrier B1)
        {
            float4* og4 = (float4*)og;
            #pragma unroll
            for (int v = tid; v < W / 4; v += NT) {
                const int i = v * 4;
                const int k = kept[i >> 5] - 1;   // 4-aligned block stays in one chunk
                float4 o;
                o.x = (k == i    ) ? xs[i    ] : 0.0f;
                o.y = (k == i + 1) ? xs[i + 1] : 0.0f;
                o.z = (k == i + 2) ? xs[i + 2] : 0.0f;
                o.w = (k == i + 3) ? xs[i + 3] : 0.0f;
                og4[v] = o;
            }
        }
    } else {
        // ---------- generic fallback (any dist): proven R1 serial-greedy ----------
        for (int i = tid; i < W; i += NT) og[i] = 0.0f;
        for (int i = tid; i < W; i += NT) {
            const float xi = xs[i];
            const bool right = (i < W - 1) ? (xs[i + 1] > xi) : false;
            const bool left  = (i > 0)     ? (xi <= xs[i - 1]) : true;
            const bool s = (xi <= 0.0f);
            const bool valley = right && left && s;
            const bool peak   = !right && !left && !s;
            const unsigned ab = __float_as_uint(xi) & 0x7fffffffu;
            key[i] = (valley || peak) ? (((u64)ab << 32) | (u64)(unsigned)(W - 1 - i)) : 0ull;
        }
        __syncthreads();

        for (;;) {
            u64 m = 0ull;
            #pragma unroll
            for (int j = 0; j < W / NT; ++j) {
                const u64 k = key[tid + j * NT];
                if (k > m) m = k;
            }
            #pragma unroll
            for (int off = 32; off > 0; off >>= 1) {
                const u64 o = __shfl_down(m, off, 64);
                if (o > m) m = o;
            }
            if ((tid & 63) == 0) red[tid >> 6] = m;
            __syncthreads();
            if (tid == 0) {
                u64 w0 = red[0];
                #pragma unroll
                for (int w2 = 1; w2 < NT / 64; ++w2) if (red[w2] > w0) w0 = red[w2];
                red[0] = w0;
            }
            __syncthreads();
            const u64 win = red[0];
            if (win == 0ull) break;

            const int p = (W - 1) - (int)(win & 0xffffffffu);
            if (tid == 0) og[p] = xs[p];

            int lo = p - dist; lo = lo < 0 ? 0 : lo;
            int hi = p + dist; hi = hi > (W - 1) ? (W - 1) : hi;
            for (int j = lo + tid; j <= hi; j += NT) key[j] = 0ull;
            __syncthreads();
        }
    }
}

extern "C" void kernel_launch(void* const* d_in, const int* in_sizes, int n_in,
                              void* d_out, int out_size, void* d_ws, size_t ws_size,
                              hipStream_t stream) {
    const float* x      = (const float*)d_in[0];
    const int*   dist_p = (const int*)d_in[1];
    float*       out    = (float*)d_out;
    const int nsig = in_sizes[0] / W;   // 128 signals of length 4096
    hipLaunchKernelGGL(extrema_nms_kernel, dim3(nsig), dim3(NT), 0, stream,
                       x, dist_p, out);
}